// Round 12
// baseline (27.628 us; speedup 1.0000x reference)
//
#include <hip/hip_runtime.h>

#define NSTROKES 64
#define NSAMP    50
#define CANVAS   512
#define HW       (CANVAS * CANVAS)
#define TPB      1024                  // 512 px x 2 stroke-groups, 16 waves
#define SPW      (NSTROKES / 16)       // 4 strokes per wave (stage A)
#define LSTRIDE  64                    // float2 slots per stroke list

// ---------------------------------------------------------------------------
// ROUND-12 PROBE: round-10 kernel (best known, 18.08us) with stage A executed
// 3x. Passes 2-3 read inputs through asm-obfuscated pointers so the compiler
// must recompute everything; all LDS writes are idempotent (each wave owns
// disjoint strokes; identical values) -> output bit-identical to round 10.
// dur = base + 2*stageA  =>  attributes stage-A cost exactly.
// ---------------------------------------------------------------------------

__device__ __forceinline__ void stage_a(
    const float* __restrict__ strokes, const float* __restrict__ widths,
    const float* __restrict__ colors,
    float2* slist, float4* scull, float4* scol,
    int wave, int lane, float fy)
{
    #pragma unroll
    for (int i = 0; i < SPW; ++i) {
        const int s = wave * SPW + i;        // stroke id 0..63

        float4 a = ((const float4*)strokes)[s * 2];       // p0x,p0y,p1x,p1y
        float4 b = ((const float4*)strokes)[s * 2 + 1];   // p2x,p2y,p3x,p3y
        const float S = (float)CANVAS;
        float c0x = a.x * S;
        float c1x = 3.0f * (a.z - a.x) * S;
        float c2x = 3.0f * (b.x - 2.0f * a.z + a.x) * S;
        float c3x = (b.z - 3.0f * b.x + 3.0f * a.z - a.x) * S;
        float c0y = a.y * S;
        float c1y = 3.0f * (a.w - a.y) * S;
        float c2y = 3.0f * (b.y - 2.0f * a.w + a.y) * S;
        float c3y = (b.w - 3.0f * b.y + 3.0f * a.w - a.y) * S;

        float w   = widths[s];
        float cut = w + 10.0f;               // alpha <= sigmoid(-20) ~ 2e-9 beyond

        float t   = (float)lane * (1.0f / (float)(NSAMP - 1));
        float px_ = fmaf(fmaf(fmaf(c3x, t, c2x), t, c1x), t, c0x);
        float py_ = fmaf(fmaf(fmaf(c3y, t, c2y), t, c1y), t, c0y);

        bool keep = (lane < NSAMP) && (fabsf(py_ - fy) <= cut);
        unsigned long long mask = __ballot(keep);
        int idx = __popcll(mask & ((1ull << lane) - 1ull));
        if (keep) {
            slist[s * LSTRIDE + idx] = make_float2(px_, py_);
        } else if (lane >= NSAMP) {
            // lanes 50..63: idx == kc for all -> consecutive sentinel slots
            slist[s * LSTRIDE + idx + (lane - NSAMP)] = make_float2(1e15f, 1e15f);
        }

        if (mask) {
            float vmn = keep ? px_ : 1e30f;
            float vmx = keep ? px_ : -1e30f;
            #pragma unroll
            for (int off = 32; off; off >>= 1) {
                vmn = fminf(vmn, __shfl_xor(vmn, off));
                vmx = fmaxf(vmx, __shfl_xor(vmx, off));
            }
            if (lane == 0) {
                scull[s] = make_float4(vmn - cut, vmx + cut, w,
                                       (float)__popcll(mask));
                scol [s] = make_float4(colors[3*s], colors[3*s+1],
                                       colors[3*s+2], 0.0f);
            }
        } else if (lane == 0) {
            scull[s] = make_float4(0.0f, 0.0f, w, 0.0f);   // cnt=0 -> culled
        }
    }
}

__global__ __launch_bounds__(TPB, 8) void raster_fused_kernel(
    const float* __restrict__ strokes,   // (64,4,2)
    const float* __restrict__ widths,    // (64,)
    const float* __restrict__ colors,    // (64,3)
    float* __restrict__ out)             // (1,3,512,512)
{
    __shared__ __align__(16) float2 slist[NSTROKES * LSTRIDE];  // 32 KB
    __shared__ float4 scull[NSTROKES];   // xmin-cut, xmax+cut, w, cnt
    __shared__ float4 scol [NSTROKES];   // r,g,b,pad

    const int tid  = threadIdx.x;
    const int wave = tid >> 6;
    const int lane = tid & 63;
    const int px   = tid & 511;
    const int grp  = tid >> 9;           // 0: strokes 0-31, 1: strokes 32-63
    const int y    = blockIdx.x;
    const float fy = (float)y;

    // ---- stage A pass 1 (the real one)
    stage_a(strokes, widths, colors, slist, scull, scol, wave, lane, fy);

    // ---- probe passes 2 and 3: opaque pointers defeat CSE; idempotent writes
    {
        const float* ps = strokes; const float* pw = widths; const float* pc = colors;
        asm volatile("" : "+s"(ps), "+s"(pw), "+s"(pc));
        stage_a(ps, pw, pc, slist, scull, scol, wave, lane, fy);
        asm volatile("" : "+s"(ps), "+s"(pw), "+s"(pc));
        stage_a(ps, pw, pc, slist, scull, scol, wave, lane, fy);
    }
    __syncthreads();

    // ---- stage B: lane l tests stroke grp*32+(l&31); 32-bit live mask
    const float fx      = (float)px;
    const float span_lo = (float)((wave & 7) << 6);
    const float span_hi = span_lo + 63.0f;
    const int   sbase   = grp << 5;

    float4 cbl = scull[sbase + (lane & 31)];
    bool alive = (cbl.w > 0.0f) && (cbl.x <= span_hi) && (cbl.y >= span_lo);
    unsigned int live = (unsigned int)__ballot(alive);   // low 32 == high 32

    float A = 1.0f, br = 0.0f, bg = 0.0f, bb = 0.0f;

    while (live) {
        // pop up to TWO live strokes (ascending ids: composite order kept)
        const int s0 = sbase + (__ffs(live) - 1);
        live &= live - 1u;
        const bool has1 = (live != 0u);
        const int s1 = has1 ? (sbase + (__ffs(live) - 1)) : s0;
        if (has1) live &= live - 1u;

        // independent LDS reads issue back-to-back (2x MLP)
        float4 cb0  = scull[s0];
        float4 cb1  = scull[s1];
        float4 col0 = scol [s0];
        float4 col1 = scol [s1];
        const int   kc0 = (int)cb0.w;
        const int   kc1 = has1 ? (int)cb1.w : 0;
        const float w0  = cb0.z;
        const float w1  = cb1.z;

        float m0 = 1e30f, m1 = 1e30f;
        const float4* L0 = (const float4*)(slist + s0 * LSTRIDE);
        const float4* L1 = (const float4*)(slist + s1 * LSTRIDE);

        const int kmax = kc0 > kc1 ? kc0 : kc1;
        for (int j = 0; j < kmax; j += 4) {        // sentinel-padded to 4
            if (j < kc0) {                          // wave-uniform branch
                float4 q0 = L0[(j >> 1)];
                float4 q1 = L0[(j >> 1) + 1];
                float dy0 = fy - q0.y, dy1 = fy - q0.w;
                float dy2 = fy - q1.y, dy3 = fy - q1.w;
                float d0  = fx - q0.x, d1  = fx - q0.z;
                float d2  = fx - q1.x, d3  = fx - q1.z;
                float a01 = fminf(fmaf(d0, d0, dy0*dy0), fmaf(d1, d1, dy1*dy1));
                float a23 = fminf(fmaf(d2, d2, dy2*dy2), fmaf(d3, d3, dy3*dy3));
                m0 = fminf(fminf(a01, a23), m0);
            }
            if (j < kc1) {                          // wave-uniform branch
                float4 q0 = L1[(j >> 1)];
                float4 q1 = L1[(j >> 1) + 1];
                float dy0 = fy - q0.y, dy1 = fy - q0.w;
                float dy2 = fy - q1.y, dy3 = fy - q1.w;
                float d0  = fx - q0.x, d1  = fx - q0.z;
                float d2  = fx - q1.x, d3  = fx - q1.z;
                float a01 = fminf(fmaf(d0, d0, dy0*dy0), fmaf(d1, d1, dy1*dy1));
                float a23 = fminf(fmaf(d2, d2, dy2*dy2), fmaf(d3, d3, dy3*dy3));
                m1 = fminf(fminf(a01, a23), m1);
            }
        }

        // both alphas compute with ILP; blend strictly s0 then s1
        float al0 = __builtin_amdgcn_rcpf(1.0f + __expf(2.0f * (sqrtf(m0) - w0)));
        float al1 = __builtin_amdgcn_rcpf(1.0f + __expf(2.0f * (sqrtf(m1) - w1)));

        A  *= (1.0f - al0);
        br  = fmaf(al0, col0.x - br, br);
        bg  = fmaf(al0, col0.y - bg, bg);
        bb  = fmaf(al0, col0.z - bb, bb);
        if (has1) {
            A  *= (1.0f - al1);
            br  = fmaf(al1, col1.x - br, br);
            bg  = fmaf(al1, col1.y - bg, bg);
            bb  = fmaf(al1, col1.z - bb, bb);
        }
    }

    // ---- combine: g0 publishes (A,B) via LDS (slist is dead), g1 folds
    __syncthreads();
    float4* xfer = (float4*)slist;           // 512 x float4 = 8 KB
    if (grp == 0) {
        xfer[px] = make_float4(A, br, bg, bb);
    }
    __syncthreads();
    if (grp == 1) {
        float4 g0 = xfer[px];
        // white canvas: c0 = A0*1 + B0; then c = A1*c0 + B1
        float cr = fmaf(A, g0.x + g0.y, br);
        float cg = fmaf(A, g0.x + g0.z, bg);
        float cb = fmaf(A, g0.x + g0.w, bb);
        const int base = y * CANVAS + px;
        out[0*HW + base] = cr;
        out[1*HW + base] = cg;
        out[2*HW + base] = cb;
    }
}

extern "C" void kernel_launch(void* const* d_in, const int* in_sizes, int n_in,
                              void* d_out, int out_size, void* d_ws, size_t ws_size,
                              hipStream_t stream) {
    const float* strokes = (const float*)d_in[0];
    const float* widths  = (const float*)d_in[1];
    const float* colors  = (const float*)d_in[2];
    float* out = (float*)d_out;

    raster_fused_kernel<<<dim3(CANVAS), dim3(TPB), 0, stream>>>(
        strokes, widths, colors, out);
}

// Round 13
// 18.479 us; speedup vs baseline: 1.4951x; 1.4951x over previous
//
#include <hip/hip_runtime.h>

#define NSTROKES 64
#define NSAMP    50
#define CANVAS   512
#define HW       (CANVAS * CANVAS)
#define TPB      1024                  // 512 px x 2 stroke-groups, 16 waves
#define SPW      (NSTROKES / 16)       // 4 strokes per wave (stage A)
#define LSTRIDE  64                    // float2 slots per stroke list

// ---------------------------------------------------------------------------
// Single kernel, one block per canvas row. tid = px + 512*grp; grp g
// composites strokes g*32..g*32+31 (affine map c -> A*c + B), folded in LDS:
// c = A1*(A0*white + B0) + B1.
//  stage A: ballot compaction of row-band samples into LDS lists (sentinels
//           at kc..kc+13). NEW: per-stroke 8-bit SPAN-OCCUPANCY MASK via 8
//           independent ballots (replaces the 12-step shuffle min/max reduce
//           -- the long cross-lane dependency chain the r12 probe exposed).
//           smask[s] = (kc<<8) | spanmask;  scol[s] = (r,g,b,w).
//  stage B: liveness = (smask >> span) & 1 (tighter than any interval test);
//           2 strokes in flight per iteration (r10's MLP).
// ---------------------------------------------------------------------------
__global__ __launch_bounds__(TPB, 8) void raster_fused_kernel(
    const float* __restrict__ strokes,   // (64,4,2)
    const float* __restrict__ widths,    // (64,)
    const float* __restrict__ colors,    // (64,3)
    float* __restrict__ out)             // (1,3,512,512)
{
    __shared__ __align__(16) float2 slist[NSTROKES * LSTRIDE];  // 32 KB
    __shared__ unsigned int smask[NSTROKES];   // (kc<<8) | 8-bit span mask
    __shared__ float4       scol [NSTROKES];   // r,g,b,w

    const int tid  = threadIdx.x;
    const int wave = tid >> 6;
    const int lane = tid & 63;
    const int px   = tid & 511;
    const int grp  = tid >> 9;           // 0: strokes 0-31, 1: strokes 32-63
    const int y    = blockIdx.x;
    const float fy = (float)y;

    // ---- stage A: compaction + span-mask, SPW strokes per wave
    #pragma unroll
    for (int i = 0; i < SPW; ++i) {
        const int s = wave * SPW + i;        // stroke id 0..63

        float4 a = ((const float4*)strokes)[s * 2];       // p0x,p0y,p1x,p1y
        float4 b = ((const float4*)strokes)[s * 2 + 1];   // p2x,p2y,p3x,p3y
        const float S = (float)CANVAS;
        float c0x = a.x * S;
        float c1x = 3.0f * (a.z - a.x) * S;
        float c2x = 3.0f * (b.x - 2.0f * a.z + a.x) * S;
        float c3x = (b.z - 3.0f * b.x + 3.0f * a.z - a.x) * S;
        float c0y = a.y * S;
        float c1y = 3.0f * (a.w - a.y) * S;
        float c2y = 3.0f * (b.y - 2.0f * a.w + a.y) * S;
        float c3y = (b.w - 3.0f * b.y + 3.0f * a.w - a.y) * S;

        float w   = widths[s];
        float cut = w + 10.0f;               // alpha <= sigmoid(-20) ~ 2e-9 beyond

        float t   = (float)lane * (1.0f / (float)(NSAMP - 1));
        float px_ = fmaf(fmaf(fmaf(c3x, t, c2x), t, c1x), t, c0x);
        float py_ = fmaf(fmaf(fmaf(c3y, t, c2y), t, c1y), t, c0y);

        bool keep = (lane < NSAMP) && (fabsf(py_ - fy) <= cut);
        unsigned long long kmask = __ballot(keep);
        int idx = __popcll(kmask & ((1ull << lane) - 1ull));
        if (keep) {
            slist[s * LSTRIDE + idx] = make_float2(px_, py_);
        } else if (lane >= NSAMP) {
            // lanes 50..63: idx == kc for all -> consecutive sentinel slots
            slist[s * LSTRIDE + idx + (lane - NSAMP)] = make_float2(1e15f, 1e15f);
        }

        // span-occupancy: sample touches spans k0..k1 (<= 2 of them);
        // 8 independent ballots, no cross-lane dependency chain.
        const int k0 = ((int)fmaxf(px_ - cut, 0.0f))   >> 6;
        const int k1 = ((int)fminf(px_ + cut, 511.0f)) >> 6;
        unsigned int mb = 0u;
        #pragma unroll
        for (int bb = 0; bb < 8; ++bb)
            mb |= (__ballot(keep && (k0 <= bb) && (bb <= k1)) != 0ull)
                      ? (1u << bb) : 0u;

        if (lane == 0) {
            smask[s] = ((unsigned int)__popcll(kmask) << 8) | mb;
            scol [s] = make_float4(colors[3*s], colors[3*s+1],
                                   colors[3*s+2], w);
        }
    }
    __syncthreads();

    // ---- stage B: liveness from span mask; 2 strokes in flight
    const float fx    = (float)px;
    const int   sg    = wave & 7;        // this wave's 64-px span
    const int   sbase = grp << 5;

    const unsigned int hdr_l = smask[sbase + (lane & 31)];
    unsigned int live = (unsigned int)__ballot((hdr_l >> sg) & 1u);

    float A = 1.0f, br = 0.0f, bg = 0.0f, bb = 0.0f;

    while (live) {
        // pop up to TWO live strokes (ascending ids: composite order kept)
        const int s0 = sbase + (__ffs(live) - 1);
        live &= live - 1u;
        const bool has1 = (live != 0u);
        const int s1 = has1 ? (sbase + (__ffs(live) - 1)) : s0;
        if (has1) live &= live - 1u;

        // independent LDS reads issue back-to-back (2x MLP)
        const unsigned int h0 = smask[s0];
        const unsigned int h1 = smask[s1];
        float4 col0 = scol[s0];
        float4 col1 = scol[s1];
        const int   kc0 = (int)(h0 >> 8);
        const int   kc1 = has1 ? (int)(h1 >> 8) : 0;
        const float w0  = col0.w;
        const float w1  = col1.w;

        float m0 = 1e30f, m1 = 1e30f;
        const float4* L0 = (const float4*)(slist + s0 * LSTRIDE);
        const float4* L1 = (const float4*)(slist + s1 * LSTRIDE);

        const int kmax = kc0 > kc1 ? kc0 : kc1;
        for (int j = 0; j < kmax; j += 4) {        // sentinel-padded to 4
            if (j < kc0) {                          // wave-uniform branch
                float4 q0 = L0[(j >> 1)];
                float4 q1 = L0[(j >> 1) + 1];
                float dy0 = fy - q0.y, dy1 = fy - q0.w;
                float dy2 = fy - q1.y, dy3 = fy - q1.w;
                float d0  = fx - q0.x, d1  = fx - q0.z;
                float d2  = fx - q1.x, d3  = fx - q1.z;
                float a01 = fminf(fmaf(d0, d0, dy0*dy0), fmaf(d1, d1, dy1*dy1));
                float a23 = fminf(fmaf(d2, d2, dy2*dy2), fmaf(d3, d3, dy3*dy3));
                m0 = fminf(fminf(a01, a23), m0);
            }
            if (j < kc1) {                          // wave-uniform branch
                float4 q0 = L1[(j >> 1)];
                float4 q1 = L1[(j >> 1) + 1];
                float dy0 = fy - q0.y, dy1 = fy - q0.w;
                float dy2 = fy - q1.y, dy3 = fy - q1.w;
                float d0  = fx - q0.x, d1  = fx - q0.z;
                float d2  = fx - q1.x, d3  = fx - q1.z;
                float a01 = fminf(fmaf(d0, d0, dy0*dy0), fmaf(d1, d1, dy1*dy1));
                float a23 = fminf(fmaf(d2, d2, dy2*dy2), fmaf(d3, d3, dy3*dy3));
                m1 = fminf(fminf(a01, a23), m1);
            }
        }

        // both alphas compute with ILP; blend strictly s0 then s1
        float al0 = __builtin_amdgcn_rcpf(1.0f + __expf(2.0f * (sqrtf(m0) - w0)));
        float al1 = __builtin_amdgcn_rcpf(1.0f + __expf(2.0f * (sqrtf(m1) - w1)));

        A  *= (1.0f - al0);
        br  = fmaf(al0, col0.x - br, br);
        bg  = fmaf(al0, col0.y - bg, bg);
        bb  = fmaf(al0, col0.z - bb, bb);
        if (has1) {
            A  *= (1.0f - al1);
            br  = fmaf(al1, col1.x - br, br);
            bg  = fmaf(al1, col1.y - bg, bg);
            bb  = fmaf(al1, col1.z - bb, bb);
        }
    }

    // ---- combine: g0 publishes (A,B) via LDS (slist is dead), g1 folds
    __syncthreads();
    float4* xfer = (float4*)slist;           // 512 x float4 = 8 KB
    if (grp == 0) {
        xfer[px] = make_float4(A, br, bg, bb);
    }
    __syncthreads();
    if (grp == 1) {
        float4 g0 = xfer[px];
        // white canvas: c0 = A0*1 + B0; then c = A1*c0 + B1
        float cr = fmaf(A, g0.x + g0.y, br);
        float cg = fmaf(A, g0.x + g0.z, bg);
        float cb = fmaf(A, g0.x + g0.w, bb);
        const int base = y * CANVAS + px;
        out[0*HW + base] = cr;
        out[1*HW + base] = cg;
        out[2*HW + base] = cb;
    }
}

extern "C" void kernel_launch(void* const* d_in, const int* in_sizes, int n_in,
                              void* d_out, int out_size, void* d_ws, size_t ws_size,
                              hipStream_t stream) {
    const float* strokes = (const float*)d_in[0];
    const float* widths  = (const float*)d_in[1];
    const float* colors  = (const float*)d_in[2];
    float* out = (float*)d_out;

    raster_fused_kernel<<<dim3(CANVAS), dim3(TPB), 0, stream>>>(
        strokes, widths, colors, out);
}